// Round 11
// baseline (368.692 us; speedup 1.0000x reference)
//
#include <hip/hip_runtime.h>
#include <hip/hip_cooperative_groups.h>
#include <stdint.h>
#include <math.h>

namespace cg = cooperative_groups;
typedef unsigned long long ull;

#define BB 16
#define NN 100000
#define DD 25
#define CC 20
#define KK 500
#define NCAND 2048
#define NBIN 5120
#define EXPBASE (122 << 10)  // min (f32exp<<10) of a score in (0.049, 1); shift 13
#define NBLK 256
#define NTHR 1024
#define RPB 6250             // rows per block-slice (NN / 16)
#define THRC 0.05
#define THRN 0.5

// Exact f64 score, replicating reference op order (candidates only).
__device__ __forceinline__ double score_f64(const float* row) {
    double m = (double)row[5];
#pragma unroll
    for (int i = 1; i < CC; ++i) m = fmax(m, (double)row[5 + i]);
    double s = 0.0;
#pragma unroll
    for (int i = 0; i < CC; ++i) s += exp((double)row[5 + i] - m);
    double conf = 1.0 / (1.0 + exp(-(double)row[4]));
    return conf * (1.0 / s);
}

// Fast f32 approx score (error ~32 ulp << 8192-ulp histogram bins).
__device__ __forceinline__ float score_f32(const float* row) {
    float m = row[5];
#pragma unroll
    for (int i = 1; i < CC; ++i) m = fmaxf(m, row[5 + i]);
    float s = 0.0f;
#pragma unroll
    for (int i = 0; i < CC; ++i) s += __expf(row[5 + i] - m);
    float conf = 1.0f / (1.0f + __expf(-row[4]));
    return conf / s;
}

__device__ __forceinline__ void decode_box(const float* row, double* o) {
    double cx = 1.0 / (1.0 + exp(-(double)row[0]));
    double cy = 1.0 / (1.0 + exp(-(double)row[1]));
    double w = 1.0 / (1.0 + exp(-(double)row[2]));
    double h = 1.0 / (1.0 + exp(-(double)row[3]));
    o[0] = cx - 0.5 * w;
    o[1] = cy - 0.5 * h;
    o[2] = cx + 0.5 * w;
    o[3] = cy + 0.5 * h;
}

__device__ __forceinline__ int argmax_cls(const float* row) {
    float mm = row[5];
    int am = 0;
#pragma unroll
    for (int c = 1; c < CC; ++c) {
        float v = row[5 + c];
        if (v > mm) { mm = v; am = c; }
    }
    return am;
}

struct Params {
    const float* outs;
    float* out;
    uint32_t* keys;
    uint32_t* ghist;   // [NBLK][NBIN] per-block slices (plain stores, no zeroing)
    uint32_t* meta;    // [BB][2] threshold, total
    uint32_t* cnt;     // [BB]
    ull* cand64;
    uint32_t* candidx;
    double* cbox;
    int* clab;
    double* sdsc;
    double* sbL; double* sbT; double* sbR; double* sbD;
    int* slab;
    ull* bsup;
};

__global__ __launch_bounds__(NTHR, 4) void mega_kernel(Params p) {
    cg::grid_group grd = cg::this_grid();
    const int tid = threadIdx.x;
    const int bid = blockIdx.x;
    __shared__ __align__(16) char smem[46336];
    __shared__ ull keepw[8];
    __shared__ int sh_b;
    __shared__ uint32_t zbase;

    // ================= P1: score (f32) + keys + per-block histogram ========
    {
        const int b = bid >> 4;
        const int sub = bid & 15;
        float* tile = (float*)smem;                   // 256 rows x 25 = 25600 B
        uint32_t* lhist = (uint32_t*)(smem + 25600);  // 5120 x 4 = 20480 B
        for (int v = tid; v < NBIN; v += NTHR) lhist[v] = 0;
        if (bid == 0 && tid < BB) p.cnt[tid] = 0;
        __syncthreads();
        const int rbase = sub * RPB;
        for (int ch = 0; ch < 25; ++ch) {             // 25*256 >= 6250
            int r0 = rbase + ch * 256;
            int nrows = RPB - ch * 256;
            if (nrows > 256) nrows = 256;
            if (nrows <= 0) break;
            // stage nrows*25 floats as float2 (r0 even -> 8B-aligned, exact count)
            const float2* src2 = (const float2*)(p.outs + ((size_t)b * NN + r0) * DD);
            float2* t2 = (float2*)tile;
            const int nf2 = (nrows * DD) >> 1;
            for (int f = tid; f < nf2; f += NTHR) t2[f] = src2[f];
            __syncthreads();
            if (tid < nrows) {
                const float* row = tile + tid * DD;
                float sc = score_f32(row);
                uint32_t key = 0;
                if (sc > 0.049f) {  // loose pre-mask; exact 0.05 decided in f64
                    key = __float_as_uint(sc);
                    int bin = (int)(key >> 13) - EXPBASE;
                    bin = bin < 0 ? 0 : (bin > NBIN - 1 ? NBIN - 1 : bin);
                    atomicAdd(&lhist[bin], 1u);
                }
                p.keys[(size_t)b * NN + r0 + tid] = key;
            }
            __syncthreads();
        }
        for (int v = tid; v < NBIN; v += NTHR)
            p.ghist[(size_t)bid * NBIN + v] = lhist[v];
    }
    grd.sync();  // ---- 1

    // ================= P2: per-batch suffix scan -> threshold T'' ==========
    if (bid < BB) {
        uint32_t* h = (uint32_t*)smem;  // 20480 B
        if (tid == 0) sh_b = 0;
        for (int v = tid; v < NBIN; v += NTHR) {
            uint32_t s = 0;
#pragma unroll
            for (int k = 0; k < 16; ++k)
                s += p.ghist[(size_t)(bid * 16 + k) * NBIN + v];
            h[v] = s;
        }
        __syncthreads();
        for (int off = 1; off < NBIN; off <<= 1) {
            uint32_t t0[5];
#pragma unroll
            for (int k = 0; k < 5; ++k) {
                int v = tid + k * NTHR;
                uint32_t s = h[v];
                if (v + off < NBIN) s += h[v + off];
                t0[k] = s;
            }
            __syncthreads();
#pragma unroll
            for (int k = 0; k < 5; ++k) h[tid + k * NTHR] = t0[k];
            __syncthreads();
        }
#pragma unroll
        for (int k = 0; k < 5; ++k) {
            int v = tid + k * NTHR;
            if (h[v] >= KK && (v == NBIN - 1 || h[v + 1] < KK)) sh_b = v;
        }
        __syncthreads();
        if (tid == 0) {
            uint32_t tot = h[0];
            int bm = sh_b > 0 ? sh_b - 1 : sh_b;  // one-bin (8192 ulp) margin
            p.meta[2 * bid] = (tot >= KK) ? (uint32_t)((EXPBASE + bm) << 13) : 1u;
            p.meta[2 * bid + 1] = tot;
        }
    }
    grd.sync();  // ---- 2

    // ================= P3: compact candidate indices =======================
    {
        const int b = bid >> 4;
        const int sub = bid & 15;
        const uint32_t T = p.meta[2 * b];
        const int iend = (sub + 1) * RPB;
        for (int i = sub * RPB + tid; i < iend; i += NTHR) {
            uint32_t key = p.keys[(size_t)b * NN + i];
            if (key != 0 && key >= T) {
                uint32_t pos = atomicAdd(&p.cnt[b], 1u);
                if (pos < NCAND) p.candidx[b * NCAND + pos] = (uint32_t)i;
            }
        }
    }
    grd.sync();  // ---- 3

    // ================= P4a: dense f64 decode (1 chain wall) ================
    {
        int s = bid * NTHR + tid;
        int b = s >> 11;
        int c = s & (NCAND - 1);
        if (b < BB) {
            uint32_t cr = p.cnt[b];
            int nc = (int)(cr < NCAND ? cr : NCAND);
            if (c < nc) {
                uint32_t i = p.candidx[b * NCAND + c];
                const float* row = p.outs + ((size_t)b * NN + i) * DD;
                double sc = score_f64(row);
                p.cand64[b * NCAND + c] =
                    (sc > THRC) ? (ull)__double_as_longlong(sc) : 0ULL;
                double o[4];
                decode_box(row, o);
                double* cb = p.cbox + ((size_t)b * NCAND + c) * 4;
                cb[0] = o[0]; cb[1] = o[1]; cb[2] = o[2]; cb[3] = o[3];
                p.clab[b * NCAND + c] = argmax_cls(row);
            }
        }
    }
    grd.sync();  // ---- 4

    // ================= P4b: exact unique rank -> top-500 + ids/boxes out ===
    if (bid < BB) {
        const int b = bid;
        ull* ckey = (ull*)smem;                       // 16384 B
        uint32_t* cidx = (uint32_t*)(smem + 16384);   // 8192 B
        uint32_t* zpref = (uint32_t*)(smem + 24576);  // 4096 B
        float* out_ids = p.out;
        float* out_boxes = p.out + BB * KK;
        uint32_t cr = p.cnt[b];
        const int nc = (int)(cr < NCAND ? cr : NCAND);
        for (int i = tid; i < nc; i += NTHR) {
            ckey[i] = p.cand64[b * NCAND + i];
            cidx[i] = p.candidx[b * NCAND + i];
        }
        __syncthreads();
        for (int c = tid; c < nc; c += NTHR) {
            ull kc = ckey[c];
            uint32_t ic = cidx[c];
            int r = 0;
            int j = 0;
            for (; j + 8 <= nc; j += 8) {
#pragma unroll
                for (int u = 0; u < 8; ++u) {
                    ull kj = ckey[j + u];
                    uint32_t ij = cidx[j + u];
                    r += (int)((kj > kc) || (kj == kc && ij < ic));
                }
            }
            for (; j < nc; ++j) {
                ull kj = ckey[j];
                uint32_t ij = cidx[j];
                r += (int)((kj > kc) || (kj == kc && ij < ic));
            }
            if (r < KK) {
                p.sdsc[b * KK + r] = __longlong_as_double((long long)kc);
                const double* cb = p.cbox + ((size_t)b * NCAND + c) * 4;
                p.sbL[b * KK + r] = cb[0];
                p.sbT[b * KK + r] = cb[1];
                p.sbR[b * KK + r] = cb[2];
                p.sbD[b * KK + r] = cb[3];
                p.slab[b * KK + r] = p.clab[b * NCAND + c];
                float* bo = out_boxes + ((size_t)b * KK + r) * 4;
                bo[0] = (float)cb[0]; bo[1] = (float)cb[1];
                bo[2] = (float)cb[2]; bo[3] = (float)cb[3];
            }
        }
        for (int i = tid; i < KK; i += NTHR) out_ids[b * KK + i] = (float)b;
        // fallback (< 500 positives): lowest-index zero-key rows fill the rest
        if (nc < KK) {
            const uint32_t* kb = p.keys + (size_t)b * NN;
            if (tid == 0) zbase = 0;
            __syncthreads();
            const uint32_t needz = (uint32_t)(KK - nc);
            for (int c0 = 0; c0 < NN; c0 += NTHR) {
                int i = c0 + tid;
                uint32_t z = (i < NN && kb[i] == 0) ? 1u : 0u;
                zpref[tid] = z;
                __syncthreads();
                for (int off = 1; off < NTHR; off <<= 1) {
                    uint32_t v = (tid >= off) ? zpref[tid - off] : 0u;
                    __syncthreads();
                    zpref[tid] += v;
                    __syncthreads();
                }
                uint32_t pos = zbase + zpref[tid] - z;
                if (z && pos < needz) {
                    int r = nc + (int)pos;
                    const float* row = p.outs + ((size_t)b * NN + i) * DD;
                    double o[4];
                    decode_box(row, o);
                    p.sdsc[b * KK + r] = 0.0;
                    p.sbL[b * KK + r] = o[0]; p.sbT[b * KK + r] = o[1];
                    p.sbR[b * KK + r] = o[2]; p.sbD[b * KK + r] = o[3];
                    p.slab[b * KK + r] = argmax_cls(row);
                    float* bo = out_boxes + ((size_t)b * KK + r) * 4;
                    bo[0] = (float)o[0]; bo[1] = (float)o[1];
                    bo[2] = (float)o[2]; bo[3] = (float)o[3];
                }
                __syncthreads();
                if (tid == 0) zbase += zpref[NTHR - 1];
                __syncthreads();
                if (zbase >= needz) break;
            }
        }
    }
    grd.sync();  // ---- 5

    // ================= P5: suppression matrix (8 block-slices per batch) ===
    if (bid < BB * 8) {
        const int b = bid >> 3;
        const int w = bid & 7;
        const int lane = tid & 63;
        const int wave = tid >> 6;
        double* Ls = (double*)smem;             // 4000 B each
        double* Ts = (double*)(smem + 4000);
        double* Rs = (double*)(smem + 8000);
        double* Ds = (double*)(smem + 12000);
        int* Lb = (int*)(smem + 16000);         // 2000 B
        for (int i = tid; i < KK; i += NTHR) {
            Ls[i] = p.sbL[b * KK + i];
            Ts[i] = p.sbT[b * KK + i];
            Rs[i] = p.sbR[b * KK + i];
            Ds[i] = p.sbD[b * KK + i];
            Lb[i] = p.slab[b * KK + i];
        }
        __syncthreads();
        const int j = w * 64 + lane;
        const bool jv = j < KK;
        double l2 = 0, t2 = 0, r2 = 0, d2 = 0, a2 = 0;
        int lj = -2;
        if (jv) {
            l2 = Ls[j]; t2 = Ts[j]; r2 = Rs[j]; d2 = Ds[j];
            lj = Lb[j];
            a2 = fmax(r2 - l2, 0.0) * fmax(d2 - t2, 0.0);
        }
        const int i0 = wave * 32;
        const int i1 = (i0 + 32 < KK) ? i0 + 32 : KK;
        for (int i = i0; i < i1; ++i) {
            double l1 = Ls[i], t1 = Ts[i], r1 = Rs[i], d1 = Ds[i];  // broadcast
            int li = Lb[i];
            bool sbit = false;
            if (jv && lj == li) {
                double a1 = fmax(r1 - l1, 0.0) * fmax(d1 - t1, 0.0);
                double iw = fmax(fmin(r1, r2) - fmax(l1, l2), 0.0);
                double ih = fmax(fmin(d1, d2) - fmax(t1, t2), 0.0);
                double inter = iw * ih;
                double uni = a1 + a2 - inter;
                sbit = inter > THRN * fmax(uni, 1e-9);  // iou > 0.5, exact
            }
            ull word = __ballot(sbit);
            if (lane == 0) p.bsup[((size_t)b * KK + i) * 8 + w] = word;
        }
    }
    grd.sync();  // ---- 6

    // ================= P6: greedy NMS (E-mask) + labels/scores out =========
    if (bid < BB) {
        const int b = bid;
        ull* sup = (ull*)smem;                   // 32000 B
        double* dscs = (double*)(smem + 32000);  // 4000 B
        int* labs = (int*)(smem + 36000);        // 2000 B
        for (int t = tid; t < KK * 8; t += NTHR) sup[t] = p.bsup[(size_t)b * KK * 8 + t];
        for (int i = tid; i < KK; i += NTHR) {
            dscs[i] = p.sdsc[b * KK + i];
            labs[i] = p.slab[b * KK + i];
        }
        __syncthreads();
        if (tid < 64) {
            const int lane = tid;
            ull kept[8];
#pragma unroll
            for (int w = 0; w < 8; ++w) kept[w] = 0ULL;
#pragma unroll
            for (int c = 0; c < 8; ++c) {
                int i = c * 64 + lane;
                bool vi = false;
                ull sprev = 0ULL, myw = 0ULL;
                if (i < KK) {
                    vi = dscs[i] > THRC;
#pragma unroll
                    for (int w = 0; w < 8; ++w)
                        if (w < c) sprev |= sup[i * 8 + w] & kept[w];
                    myw = sup[i * 8 + c];
                }
                ull E = __ballot(vi && sprev == 0ULL);  // undecided
                ull ck = 0ULL;
                while (E) {
                    int j = __ffsll((ull)E) - 1;  // lowest undecided: kept
                    ck |= 1ULL << j;
                    ull S = __ballot(((myw >> j) & 1ULL) != 0);
                    E &= ~S;
                    E &= ~(1ULL << j);
                }
                kept[c] = ck;
            }
            if (lane == 0) {
#pragma unroll
                for (int w = 0; w < 8; ++w) keepw[w] = kept[w];
            }
        }
        __syncthreads();
        float* out_labels = p.out + BB * KK * 5;
        float* out_scores = p.out + BB * KK * 6;
        for (int i = tid; i < KK; i += NTHR) {
            bool keep = (keepw[i >> 6] >> (i & 63)) & 1ULL;
            out_labels[b * KK + i] = keep ? (float)labs[i] : -1.0f;
            out_scores[b * KK + i] = keep ? (float)dscs[i] : 0.0f;
        }
    }
}

extern "C" void kernel_launch(void* const* d_in, const int* in_sizes, int n_in,
                              void* d_out, int out_size, void* d_ws, size_t ws_size,
                              hipStream_t stream) {
    char* ws = (char*)d_ws;
    Params p;
    p.outs = (const float*)d_in[0];
    p.out = (float*)d_out;
    size_t off = 0;
    p.keys = (uint32_t*)(ws + off);    off += (size_t)BB * NN * 4;          // 6.4 MB
    p.ghist = (uint32_t*)(ws + off);   off += (size_t)NBLK * NBIN * 4;      // 5.2 MB
    p.meta = (uint32_t*)(ws + off);    off += BB * 2 * 4;
    p.cnt = (uint32_t*)(ws + off);     off += BB * 4;
    p.cand64 = (ull*)(ws + off);       off += (size_t)BB * NCAND * 8;
    p.candidx = (uint32_t*)(ws + off); off += (size_t)BB * NCAND * 4;
    p.cbox = (double*)(ws + off);      off += (size_t)BB * NCAND * 4 * 8;
    p.clab = (int*)(ws + off);         off += (size_t)BB * NCAND * 4;
    p.sdsc = (double*)(ws + off);      off += (size_t)BB * KK * 8;
    p.sbL = (double*)(ws + off);       off += (size_t)BB * KK * 8;
    p.sbT = (double*)(ws + off);       off += (size_t)BB * KK * 8;
    p.sbR = (double*)(ws + off);       off += (size_t)BB * KK * 8;
    p.sbD = (double*)(ws + off);       off += (size_t)BB * KK * 8;
    p.slab = (int*)(ws + off);         off += (size_t)BB * KK * 4;
    p.bsup = (ull*)(ws + off);         off += (size_t)BB * KK * 8 * 8;

    void* args[] = {&p};
    hipLaunchCooperativeKernel((void*)mega_kernel, dim3(NBLK), dim3(NTHR),
                               args, 0, stream);
}

// Round 12
// 208.545 us; speedup vs baseline: 1.7679x; 1.7679x over previous
//
#include <hip/hip_runtime.h>
#include <stdint.h>
#include <math.h>

typedef unsigned long long ull;

#define BB 16
#define NN 100000
#define DD 25
#define CC 20
#define KK 500
#define NCAND 2048
#define NBIN 5120
#define EXPBASE (122 << 10)  // min (f32exp<<10) of a score in (0.049, 1); shift 13
#define BPB 391              // score blocks per batch (391*256 >= 100000)
#define GB3 98               // compact blocks per batch (98*1024 >= 100000)
#define THRC 0.05
#define THRN 0.5

// Exact f64 score, replicating reference op order (candidates only).
__device__ __forceinline__ double score_f64(const float* row) {
    double m = (double)row[5];
#pragma unroll
    for (int i = 1; i < CC; ++i) m = fmax(m, (double)row[5 + i]);
    double s = 0.0;
#pragma unroll
    for (int i = 0; i < CC; ++i) s += exp((double)row[5 + i] - m);
    double conf = 1.0 / (1.0 + exp(-(double)row[4]));
    return conf * (1.0 / s);
}

// Fast f32 approx score (error ~32 ulp << 8192-ulp histogram bins).
__device__ __forceinline__ float score_f32(const float* row) {
    float m = row[5];
#pragma unroll
    for (int i = 1; i < CC; ++i) m = fmaxf(m, row[5 + i]);
    float s = 0.0f;
#pragma unroll
    for (int i = 0; i < CC; ++i) s += __expf(row[5 + i] - m);
    float conf = 1.0f / (1.0f + __expf(-row[4]));
    return conf / s;
}

__device__ __forceinline__ void decode_box(const float* row, double* o) {
    double cx = 1.0 / (1.0 + exp(-(double)row[0]));
    double cy = 1.0 / (1.0 + exp(-(double)row[1]));
    double w = 1.0 / (1.0 + exp(-(double)row[2]));
    double h = 1.0 / (1.0 + exp(-(double)row[3]));
    o[0] = cx - 0.5 * w;
    o[1] = cy - 0.5 * h;
    o[2] = cx + 0.5 * w;
    o[3] = cy + 0.5 * h;
}

__device__ __forceinline__ int argmax_cls(const float* row) {
    float mm = row[5];
    int am = 0;
#pragma unroll
    for (int c = 1; c < CC; ++c) {
        float v = row[5 + c];
        if (v > mm) { mm = v; am = c; }
    }
    return am;
}

// K1: f32 approx keys only (no histogram) — pure streaming.
__global__ __launch_bounds__(256) void score_kernel(const float* __restrict__ outs,
                                                    uint32_t* __restrict__ keys) {
    __shared__ float tile[256 * DD];
    const int b = blockIdx.x / BPB;
    const int lb = blockIdx.x % BPB;
    const int start = lb << 8;
    int nrows = NN - start;
    if (nrows > 256) nrows = 256;
    const float4* src = (const float4*)(outs + ((size_t)b * NN + start) * DD);
    const int nf4 = (nrows * DD) >> 2;
    float4* dst4 = (float4*)tile;
    for (int i = threadIdx.x; i < nf4; i += 256) dst4[i] = src[i];
    __syncthreads();
    if ((int)threadIdx.x < nrows) {
        const float* row = tile + threadIdx.x * DD;
        float sc = score_f32(row);
        keys[(size_t)b * NN + start + threadIdx.x] =
            (sc > 0.049f) ? __float_as_uint(sc) : 0u;  // loose pre-mask
    }
}

// K2: per-batch histogram from keys + suffix scan -> threshold T''; zero cnt.
__global__ __launch_bounds__(1024) void scan_kernel(const uint32_t* __restrict__ keys,
                                                    uint32_t* __restrict__ meta,
                                                    uint32_t* __restrict__ cnt) {
    const int b = blockIdx.x;
    const int tid = threadIdx.x;
    __shared__ uint32_t h[NBIN];
    __shared__ int sh_b;
    for (int v = tid; v < NBIN; v += 1024) h[v] = 0;
    if (tid == 0) { sh_b = 0; cnt[b] = 0; }
    __syncthreads();
    const uint4* kb4 = (const uint4*)(keys + (size_t)b * NN);
    for (int q = tid; q < NN / 4; q += 1024) {
        uint4 k4 = kb4[q];
        uint32_t a[4] = {k4.x, k4.y, k4.z, k4.w};
#pragma unroll
        for (int c = 0; c < 4; ++c) {
            if (a[c]) {  // atomics only for ~positives
                int bin = (int)(a[c] >> 13) - EXPBASE;
                bin = bin < 0 ? 0 : (bin > NBIN - 1 ? NBIN - 1 : bin);
                atomicAdd(&h[bin], 1u);
            }
        }
    }
    __syncthreads();
    for (int off = 1; off < NBIN; off <<= 1) {
        uint32_t t0[5];
#pragma unroll
        for (int k = 0; k < 5; ++k) {
            int v = tid + k * 1024;
            uint32_t s = h[v];
            if (v + off < NBIN) s += h[v + off];
            t0[k] = s;
        }
        __syncthreads();
#pragma unroll
        for (int k = 0; k < 5; ++k) h[tid + k * 1024] = t0[k];
        __syncthreads();
    }
#pragma unroll
    for (int k = 0; k < 5; ++k) {
        int v = tid + k * 1024;
        if (h[v] >= KK && (v == NBIN - 1 || h[v + 1] < KK)) sh_b = v;
    }
    __syncthreads();
    if (tid == 0) {
        uint32_t tot = h[0];
        int bm = sh_b > 0 ? sh_b - 1 : sh_b;  // one-bin (8192 ulp) safety margin
        meta[2 * b] = (tot >= KK) ? (uint32_t)((EXPBASE + bm) << 13) : 1u;
        meta[2 * b + 1] = tot;
    }
}

// K3: cheap compaction — append candidate indices.
__global__ __launch_bounds__(1024) void compact_kernel(const uint32_t* __restrict__ keys,
                                                       const uint32_t* __restrict__ meta,
                                                       uint32_t* __restrict__ cnt,
                                                       uint32_t* __restrict__ candidx) {
    const int b = blockIdx.x / GB3;
    const int i = (blockIdx.x % GB3) * 1024 + threadIdx.x;
    if (i >= NN) return;
    uint32_t key = keys[(size_t)b * NN + i];
    if (key == 0 || key < meta[2 * b]) return;
    uint32_t pos = atomicAdd(&cnt[b], 1u);
    if (pos < NCAND) candidx[b * NCAND + pos] = (uint32_t)i;
}

// K4: fused f64 score + exact rank + winner decode + sup slice.
// 8 blocks/batch; rank work is redundant across the 8 (parallel CUs, same wall).
__global__ __launch_bounds__(1024) void ranksup_kernel(const float* __restrict__ outs,
                                                       const uint32_t* __restrict__ keys,
                                                       const uint32_t* __restrict__ cnt,
                                                       const uint32_t* __restrict__ candidx,
                                                       double* __restrict__ sdsc,
                                                       int* __restrict__ slab,
                                                       ull* __restrict__ bsup,
                                                       float* __restrict__ out) {
    const int b = blockIdx.x >> 3;
    const int w = blockIdx.x & 7;
    const int tid = threadIdx.x;
    const int lane = tid & 63;
    const int wave = tid >> 6;
    __shared__ ull ckey[NCAND];          // 16384 B
    __shared__ uint32_t cidx[NCAND];     // 8192 B
    __shared__ double Ls[KK], Ts[KK], Rs[KK], Ds[KK];  // 16000 B
    __shared__ int Lb[KK];               // 2000 B
    __shared__ uint32_t zpref[1024];     // 4096 B
    __shared__ uint32_t zbase;

    uint32_t cr = cnt[b];
    const int nc = (int)(cr < NCAND ? cr : NCAND);
    for (int i = tid; i < nc; i += 1024) cidx[i] = candidx[b * NCAND + i];
    __syncthreads();

    // phase A: dense exact f64 scores for all candidates
    for (int c = tid; c < nc; c += 1024) {
        const float* row = outs + ((size_t)b * NN + cidx[c]) * DD;
        double sc = score_f64(row);
        ckey[c] = (sc > THRC) ? (ull)__double_as_longlong(sc) : 0ULL;
    }
    __syncthreads();

    float* out_ids = out;
    float* out_boxes = out + BB * KK;

    // phase B: exact unique rank (f64 desc, idx asc) + winner-only decode
    for (int c = tid; c < nc; c += 1024) {
        ull kc = ckey[c];
        uint32_t ic = cidx[c];
        int r = 0;
        int j = 0;
        for (; j + 8 <= nc; j += 8) {
#pragma unroll
            for (int u = 0; u < 8; ++u) {
                ull kj = ckey[j + u];
                uint32_t ij = cidx[j + u];
                r += (int)((kj > kc) || (kj == kc && ij < ic));
            }
        }
        for (; j < nc; ++j) {
            ull kj = ckey[j];
            uint32_t ij = cidx[j];
            r += (int)((kj > kc) || (kj == kc && ij < ic));
        }
        if (r < KK) {
            const float* row = outs + ((size_t)b * NN + ic) * DD;
            double o[4];
            decode_box(row, o);
            Ls[r] = o[0]; Ts[r] = o[1]; Rs[r] = o[2]; Ds[r] = o[3];
            int am = argmax_cls(row);
            Lb[r] = am;
            if (w == 0) {
                sdsc[b * KK + r] = __longlong_as_double((long long)kc);
                slab[b * KK + r] = am;
                float* bo = out_boxes + ((size_t)b * KK + r) * 4;
                bo[0] = (float)o[0]; bo[1] = (float)o[1];
                bo[2] = (float)o[2]; bo[3] = (float)o[3];
            }
        }
    }
    if (w == 0)
        for (int i = tid; i < KK; i += 1024) out_ids[b * KK + i] = (float)b;
    // fallback (< 500 positives): lowest-index zero-key rows fill the rest
    if (nc < KK) {
        const uint32_t* kb = keys + (size_t)b * NN;
        if (tid == 0) zbase = 0;
        __syncthreads();
        const uint32_t needz = (uint32_t)(KK - nc);
        for (int c0 = 0; c0 < NN; c0 += 1024) {
            int i = c0 + tid;
            uint32_t z = (i < NN && kb[i] == 0) ? 1u : 0u;
            zpref[tid] = z;
            __syncthreads();
            for (int off = 1; off < 1024; off <<= 1) {
                uint32_t v = (tid >= off) ? zpref[tid - off] : 0u;
                __syncthreads();
                zpref[tid] += v;
                __syncthreads();
            }
            uint32_t pos = zbase + zpref[tid] - z;
            if (z && pos < needz) {
                int r = nc + (int)pos;
                const float* row = outs + ((size_t)b * NN + i) * DD;
                double o[4];
                decode_box(row, o);
                Ls[r] = o[0]; Ts[r] = o[1]; Rs[r] = o[2]; Ds[r] = o[3];
                int am = argmax_cls(row);
                Lb[r] = am;
                if (w == 0) {
                    sdsc[b * KK + r] = 0.0;
                    slab[b * KK + r] = am;
                    float* bo = out_boxes + ((size_t)b * KK + r) * 4;
                    bo[0] = (float)o[0]; bo[1] = (float)o[1];
                    bo[2] = (float)o[2]; bo[3] = (float)o[3];
                }
            }
            __syncthreads();
            if (tid == 0) zbase += zpref[1023];
            __syncthreads();
            if (zbase >= needz) break;
        }
    }
    __syncthreads();

    // phase C: suppression slice w (columns w*64..w*64+63)
    const int j = w * 64 + lane;
    const bool jv = j < KK;
    double l2 = 0, t2 = 0, r2 = 0, d2 = 0, a2 = 0;
    int lj = -2;
    if (jv) {
        l2 = Ls[j]; t2 = Ts[j]; r2 = Rs[j]; d2 = Ds[j];
        lj = Lb[j];
        a2 = fmax(r2 - l2, 0.0) * fmax(d2 - t2, 0.0);
    }
    const int i0 = wave * 32;
    const int i1 = (i0 + 32 < KK) ? i0 + 32 : KK;
    for (int i = i0; i < i1; ++i) {
        double l1 = Ls[i], t1 = Ts[i], r1 = Rs[i], d1 = Ds[i];  // broadcast
        int li = Lb[i];
        bool sbit = false;
        if (jv && lj == li) {
            double a1 = fmax(r1 - l1, 0.0) * fmax(d1 - t1, 0.0);
            double iw = fmax(fmin(r1, r2) - fmax(l1, l2), 0.0);
            double ih = fmax(fmin(d1, d2) - fmax(t1, t2), 0.0);
            double inter = iw * ih;
            double uni = a1 + a2 - inter;
            sbit = inter > THRN * fmax(uni, 1e-9);  // iou > 0.5, exact
        }
        ull word = __ballot(sbit);
        if (lane == 0) bsup[((size_t)b * KK + i) * 8 + w] = word;
    }
}

// K5: greedy NMS via wave-uniform E-mask + labels/scores outputs.
__global__ __launch_bounds__(512) void supnms_kernel(const double* __restrict__ sdsc,
                                                     const int* __restrict__ slab,
                                                     const ull* __restrict__ bsup,
                                                     float* __restrict__ out) {
    const int b = blockIdx.x;
    const int tid = threadIdx.x;
    __shared__ ull sup[KK * 8];
    __shared__ double dscs[KK];
    __shared__ int labs[KK];
    __shared__ ull keepw[8];
    for (int t = tid; t < KK * 8; t += 512) sup[t] = bsup[(size_t)b * KK * 8 + t];
    for (int i = tid; i < KK; i += 512) {
        dscs[i] = sdsc[b * KK + i];
        labs[i] = slab[b * KK + i];
    }
    __syncthreads();
    if (tid < 64) {
        const int lane = tid;
        ull kept[8];
#pragma unroll
        for (int w = 0; w < 8; ++w) kept[w] = 0ULL;
#pragma unroll
        for (int c = 0; c < 8; ++c) {
            int i = c * 64 + lane;
            bool vi = false;
            ull sprev = 0ULL, myw = 0ULL;
            if (i < KK) {
                vi = dscs[i] > THRC;
#pragma unroll
                for (int w = 0; w < 8; ++w)
                    if (w < c) sprev |= sup[i * 8 + w] & kept[w];
                myw = sup[i * 8 + c];
            }
            ull E = __ballot(vi && sprev == 0ULL);  // undecided
            ull ck = 0ULL;
            while (E) {
                int j = __ffsll((ull)E) - 1;  // lowest undecided: kept
                ck |= 1ULL << j;
                ull S = __ballot(((myw >> j) & 1ULL) != 0);
                E &= ~S;
                E &= ~(1ULL << j);
            }
            kept[c] = ck;
        }
        if (lane == 0) {
#pragma unroll
            for (int w = 0; w < 8; ++w) keepw[w] = kept[w];
        }
    }
    __syncthreads();
    float* out_labels = out + BB * KK * 5;
    float* out_scores = out + BB * KK * 6;
    for (int i = tid; i < KK; i += 512) {
        bool keep = (keepw[i >> 6] >> (i & 63)) & 1ULL;
        out_labels[b * KK + i] = keep ? (float)labs[i] : -1.0f;
        out_scores[b * KK + i] = keep ? (float)dscs[i] : 0.0f;
    }
}

extern "C" void kernel_launch(void* const* d_in, const int* in_sizes, int n_in,
                              void* d_out, int out_size, void* d_ws, size_t ws_size,
                              hipStream_t stream) {
    const float* outs = (const float*)d_in[0];
    float* out = (float*)d_out;
    char* ws = (char*)d_ws;

    uint32_t* keys = (uint32_t*)ws;                            // 6.4 MB
    size_t off = (size_t)BB * NN * 4;
    uint32_t* meta = (uint32_t*)(ws + off);  off += BB * 2 * 4;
    uint32_t* cnt = (uint32_t*)(ws + off);   off += BB * 4;
    uint32_t* candidx = (uint32_t*)(ws + off); off += (size_t)BB * NCAND * 4;
    double* sdsc = (double*)(ws + off);      off += (size_t)BB * KK * 8;
    int* slab = (int*)(ws + off);            off += (size_t)BB * KK * 4;
    ull* bsup = (ull*)(ws + off);            off += (size_t)BB * KK * 8 * 8;

    score_kernel<<<BB * BPB, 256, 0, stream>>>(outs, keys);
    scan_kernel<<<BB, 1024, 0, stream>>>(keys, meta, cnt);
    compact_kernel<<<BB * GB3, 1024, 0, stream>>>(keys, meta, cnt, candidx);
    ranksup_kernel<<<BB * 8, 1024, 0, stream>>>(outs, keys, cnt, candidx,
                                                sdsc, slab, bsup, out);
    supnms_kernel<<<BB, 512, 0, stream>>>(sdsc, slab, bsup, out);
}

// Round 13
// 138.514 us; speedup vs baseline: 2.6618x; 1.5056x over previous
//
#include <hip/hip_runtime.h>
#include <stdint.h>
#include <math.h>

typedef unsigned long long ull;

#define BB 16
#define NN 100000
#define DD 25
#define CC 20
#define KK 500
#define NCAND 2048
#define NBIN 5120
#define EXPBASE (122 << 10)  // min (f32exp<<10) of a score in (0.049, 1); shift 13
#define BPB 196              // score blocks per batch (196*512 >= 100000)
#define THRC 0.05
#define THRN 0.5

// Exact f64 score, replicating reference op order (candidates only).
__device__ __forceinline__ double score_f64(const float* row) {
    double m = (double)row[5];
#pragma unroll
    for (int i = 1; i < CC; ++i) m = fmax(m, (double)row[5 + i]);
    double s = 0.0;
#pragma unroll
    for (int i = 0; i < CC; ++i) s += exp((double)row[5 + i] - m);
    double conf = 1.0 / (1.0 + exp(-(double)row[4]));
    return conf * (1.0 / s);
}

// Fast f32 approx score (error ~32 ulp << 8192-ulp histogram bins).
__device__ __forceinline__ float score_f32(const float* row) {
    float m = row[5];
#pragma unroll
    for (int i = 1; i < CC; ++i) m = fmaxf(m, row[5 + i]);
    float s = 0.0f;
#pragma unroll
    for (int i = 0; i < CC; ++i) s += __expf(row[5 + i] - m);
    float conf = 1.0f / (1.0f + __expf(-row[4]));
    return conf / s;
}

__device__ __forceinline__ void decode_box(const float* row, double* o) {
    double cx = 1.0 / (1.0 + exp(-(double)row[0]));
    double cy = 1.0 / (1.0 + exp(-(double)row[1]));
    double w = 1.0 / (1.0 + exp(-(double)row[2]));
    double h = 1.0 / (1.0 + exp(-(double)row[3]));
    o[0] = cx - 0.5 * w;
    o[1] = cy - 0.5 * h;
    o[2] = cx + 0.5 * w;
    o[3] = cy + 0.5 * h;
}

__device__ __forceinline__ int argmax_cls(const float* row) {
    float mm = row[5];
    int am = 0;
#pragma unroll
    for (int c = 1; c < CC; ++c) {
        float v = row[5 + c];
        if (v > mm) { mm = v; am = c; }
    }
    return am;
}

// K1: f32 approx keys only — pure streaming (512 rows / 512 threads per block).
__global__ __launch_bounds__(512) void score_kernel(const float* __restrict__ outs,
                                                    uint32_t* __restrict__ keys) {
    __shared__ float tile[512 * DD];
    const int b = blockIdx.x / BPB;
    const int lb = blockIdx.x % BPB;
    const int start = lb << 9;
    int nrows = NN - start;
    if (nrows > 512) nrows = 512;
    const float4* src = (const float4*)(outs + ((size_t)b * NN + start) * DD);
    const int nf4 = (nrows * DD) >> 2;  // 512*25/4=3200, 160*25/4=1000: exact
    float4* dst4 = (float4*)tile;
    for (int i = threadIdx.x; i < nf4; i += 512) dst4[i] = src[i];
    __syncthreads();
    if ((int)threadIdx.x < nrows) {
        const float* row = tile + threadIdx.x * DD;
        float sc = score_f32(row);
        keys[(size_t)b * NN + start + threadIdx.x] =
            (sc > 0.049f) ? __float_as_uint(sc) : 0u;  // loose pre-mask
    }
}

// K2: histogram + suffix scan -> T'' + fused compaction (keys are L2-resident).
__global__ __launch_bounds__(1024) void scan_kernel(const uint32_t* __restrict__ keys,
                                                    uint32_t* __restrict__ meta,
                                                    uint32_t* __restrict__ cnt,
                                                    uint32_t* __restrict__ candidx) {
    const int b = blockIdx.x;
    const int tid = threadIdx.x;
    __shared__ uint32_t h[NBIN];
    __shared__ int sh_b;
    __shared__ uint32_t lcnt;
    for (int v = tid; v < NBIN; v += 1024) h[v] = 0;
    if (tid == 0) { sh_b = 0; lcnt = 0; }
    __syncthreads();
    const uint4* kb4 = (const uint4*)(keys + (size_t)b * NN);
    for (int q = tid; q < NN / 4; q += 1024) {
        uint4 k4 = kb4[q];
        uint32_t a[4] = {k4.x, k4.y, k4.z, k4.w};
#pragma unroll
        for (int c = 0; c < 4; ++c) {
            if (a[c]) {  // atomics only for positives
                int bin = (int)(a[c] >> 13) - EXPBASE;
                bin = bin < 0 ? 0 : (bin > NBIN - 1 ? NBIN - 1 : bin);
                atomicAdd(&h[bin], 1u);
            }
        }
    }
    __syncthreads();
    for (int off = 1; off < NBIN; off <<= 1) {
        uint32_t t0[5];
#pragma unroll
        for (int k = 0; k < 5; ++k) {
            int v = tid + k * 1024;
            uint32_t s = h[v];
            if (v + off < NBIN) s += h[v + off];
            t0[k] = s;
        }
        __syncthreads();
#pragma unroll
        for (int k = 0; k < 5; ++k) h[tid + k * 1024] = t0[k];
        __syncthreads();
    }
#pragma unroll
    for (int k = 0; k < 5; ++k) {
        int v = tid + k * 1024;
        if (h[v] >= KK && (v == NBIN - 1 || h[v + 1] < KK)) sh_b = v;
    }
    __syncthreads();
    uint32_t T;
    if (tid == 0) {
        uint32_t tot = h[0];
        int bm = sh_b > 0 ? sh_b - 1 : sh_b;  // one-bin (8192 ulp) safety margin
        T = (tot >= KK) ? (uint32_t)((EXPBASE + bm) << 13) : 1u;
        meta[2 * b] = T;
        meta[2 * b + 1] = tot;
        h[0] = T;  // broadcast via LDS
    }
    __syncthreads();
    T = h[0];
    // fused compaction: second pass over the (L2-resident) keys
    for (int q = tid; q < NN / 4; q += 1024) {
        uint4 k4 = kb4[q];
        uint32_t a[4] = {k4.x, k4.y, k4.z, k4.w};
#pragma unroll
        for (int c = 0; c < 4; ++c) {
            if (a[c] != 0 && a[c] >= T) {
                uint32_t pos = atomicAdd(&lcnt, 1u);
                if (pos < NCAND) candidx[b * NCAND + pos] = (uint32_t)(4 * q + c);
            }
        }
    }
    __syncthreads();
    if (tid == 0) cnt[b] = lcnt;
}

// K3: fused f64 score + exact rank + winner decode + sup slice.
// 8 blocks/batch; rank work is redundant across the 8 (parallel CUs, same wall).
__global__ __launch_bounds__(1024) void ranksup_kernel(const float* __restrict__ outs,
                                                       const uint32_t* __restrict__ keys,
                                                       const uint32_t* __restrict__ cnt,
                                                       const uint32_t* __restrict__ candidx,
                                                       double* __restrict__ sdsc,
                                                       int* __restrict__ slab,
                                                       ull* __restrict__ bsup,
                                                       float* __restrict__ out) {
    const int b = blockIdx.x >> 3;
    const int w = blockIdx.x & 7;
    const int tid = threadIdx.x;
    const int lane = tid & 63;
    const int wave = tid >> 6;
    __shared__ ull ckey[NCAND];          // 16384 B
    __shared__ uint32_t cidx[NCAND];     // 8192 B
    __shared__ double Ls[KK], Ts[KK], Rs[KK], Ds[KK];  // 16000 B
    __shared__ int Lb[KK];               // 2000 B
    __shared__ uint32_t zpref[1024];     // 4096 B
    __shared__ uint32_t zbase;

    uint32_t cr = cnt[b];
    const int nc = (int)(cr < NCAND ? cr : NCAND);
    for (int i = tid; i < nc; i += 1024) cidx[i] = candidx[b * NCAND + i];
    __syncthreads();

    // phase A: dense exact f64 scores for all candidates
    for (int c = tid; c < nc; c += 1024) {
        const float* row = outs + ((size_t)b * NN + cidx[c]) * DD;
        double sc = score_f64(row);
        ckey[c] = (sc > THRC) ? (ull)__double_as_longlong(sc) : 0ULL;
    }
    __syncthreads();

    float* out_ids = out;
    float* out_boxes = out + BB * KK;

    // phase B: exact unique rank (f64 desc, idx asc) + winner-only decode
    for (int c = tid; c < nc; c += 1024) {
        ull kc = ckey[c];
        uint32_t ic = cidx[c];
        int r = 0;
        int j = 0;
        for (; j + 8 <= nc; j += 8) {
#pragma unroll
            for (int u = 0; u < 8; ++u) {
                ull kj = ckey[j + u];
                uint32_t ij = cidx[j + u];
                r += (int)((kj > kc) || (kj == kc && ij < ic));
            }
        }
        for (; j < nc; ++j) {
            ull kj = ckey[j];
            uint32_t ij = cidx[j];
            r += (int)((kj > kc) || (kj == kc && ij < ic));
        }
        if (r < KK) {
            const float* row = outs + ((size_t)b * NN + ic) * DD;
            double o[4];
            decode_box(row, o);
            Ls[r] = o[0]; Ts[r] = o[1]; Rs[r] = o[2]; Ds[r] = o[3];
            int am = argmax_cls(row);
            Lb[r] = am;
            if (w == 0) {
                sdsc[b * KK + r] = __longlong_as_double((long long)kc);
                slab[b * KK + r] = am;
                float* bo = out_boxes + ((size_t)b * KK + r) * 4;
                bo[0] = (float)o[0]; bo[1] = (float)o[1];
                bo[2] = (float)o[2]; bo[3] = (float)o[3];
            }
        }
    }
    if (w == 0)
        for (int i = tid; i < KK; i += 1024) out_ids[b * KK + i] = (float)b;
    // fallback (< 500 positives): lowest-index zero-key rows fill the rest
    if (nc < KK) {
        const uint32_t* kb = keys + (size_t)b * NN;
        if (tid == 0) zbase = 0;
        __syncthreads();
        const uint32_t needz = (uint32_t)(KK - nc);
        for (int c0 = 0; c0 < NN; c0 += 1024) {
            int i = c0 + tid;
            uint32_t z = (i < NN && kb[i] == 0) ? 1u : 0u;
            zpref[tid] = z;
            __syncthreads();
            for (int off = 1; off < 1024; off <<= 1) {
                uint32_t v = (tid >= off) ? zpref[tid - off] : 0u;
                __syncthreads();
                zpref[tid] += v;
                __syncthreads();
            }
            uint32_t pos = zbase + zpref[tid] - z;
            if (z && pos < needz) {
                int r = nc + (int)pos;
                const float* row = outs + ((size_t)b * NN + i) * DD;
                double o[4];
                decode_box(row, o);
                Ls[r] = o[0]; Ts[r] = o[1]; Rs[r] = o[2]; Ds[r] = o[3];
                int am = argmax_cls(row);
                Lb[r] = am;
                if (w == 0) {
                    sdsc[b * KK + r] = 0.0;
                    slab[b * KK + r] = am;
                    float* bo = out_boxes + ((size_t)b * KK + r) * 4;
                    bo[0] = (float)o[0]; bo[1] = (float)o[1];
                    bo[2] = (float)o[2]; bo[3] = (float)o[3];
                }
            }
            __syncthreads();
            if (tid == 0) zbase += zpref[1023];
            __syncthreads();
            if (zbase >= needz) break;
        }
    }
    __syncthreads();

    // phase C: suppression slice w (columns w*64..w*64+63)
    const int j = w * 64 + lane;
    const bool jv = j < KK;
    double l2 = 0, t2 = 0, r2 = 0, d2 = 0, a2 = 0;
    int lj = -2;
    if (jv) {
        l2 = Ls[j]; t2 = Ts[j]; r2 = Rs[j]; d2 = Ds[j];
        lj = Lb[j];
        a2 = fmax(r2 - l2, 0.0) * fmax(d2 - t2, 0.0);
    }
    const int i0 = wave * 32;
    const int i1 = (i0 + 32 < KK) ? i0 + 32 : KK;
    for (int i = i0; i < i1; ++i) {
        double l1 = Ls[i], t1 = Ts[i], r1 = Rs[i], d1 = Ds[i];  // broadcast
        int li = Lb[i];
        bool sbit = false;
        if (jv && lj == li) {
            double a1 = fmax(r1 - l1, 0.0) * fmax(d1 - t1, 0.0);
            double iw = fmax(fmin(r1, r2) - fmax(l1, l2), 0.0);
            double ih = fmax(fmin(d1, d2) - fmax(t1, t2), 0.0);
            double inter = iw * ih;
            double uni = a1 + a2 - inter;
            sbit = inter > THRN * fmax(uni, 1e-9);  // iou > 0.5, exact
        }
        ull word = __ballot(sbit);
        if (lane == 0) bsup[((size_t)b * KK + i) * 8 + w] = word;
    }
}

// K4: greedy NMS via wave-uniform E-mask + labels/scores outputs.
__global__ __launch_bounds__(512) void supnms_kernel(const double* __restrict__ sdsc,
                                                     const int* __restrict__ slab,
                                                     const ull* __restrict__ bsup,
                                                     float* __restrict__ out) {
    const int b = blockIdx.x;
    const int tid = threadIdx.x;
    __shared__ ull sup[KK * 8];
    __shared__ double dscs[KK];
    __shared__ int labs[KK];
    __shared__ ull keepw[8];
    for (int t = tid; t < KK * 8; t += 512) sup[t] = bsup[(size_t)b * KK * 8 + t];
    for (int i = tid; i < KK; i += 512) {
        dscs[i] = sdsc[b * KK + i];
        labs[i] = slab[b * KK + i];
    }
    __syncthreads();
    if (tid < 64) {
        const int lane = tid;
        ull kept[8];
#pragma unroll
        for (int w = 0; w < 8; ++w) kept[w] = 0ULL;
#pragma unroll
        for (int c = 0; c < 8; ++c) {
            int i = c * 64 + lane;
            bool vi = false;
            ull sprev = 0ULL, myw = 0ULL;
            if (i < KK) {
                vi = dscs[i] > THRC;
#pragma unroll
                for (int w = 0; w < 8; ++w)
                    if (w < c) sprev |= sup[i * 8 + w] & kept[w];
                myw = sup[i * 8 + c];
            }
            ull E = __ballot(vi && sprev == 0ULL);  // undecided
            ull ck = 0ULL;
            while (E) {
                int j = __ffsll((ull)E) - 1;  // lowest undecided: kept
                ck |= 1ULL << j;
                ull S = __ballot(((myw >> j) & 1ULL) != 0);
                E &= ~S;
                E &= ~(1ULL << j);
            }
            kept[c] = ck;
        }
        if (lane == 0) {
#pragma unroll
            for (int w = 0; w < 8; ++w) keepw[w] = kept[w];
        }
    }
    __syncthreads();
    float* out_labels = out + BB * KK * 5;
    float* out_scores = out + BB * KK * 6;
    for (int i = tid; i < KK; i += 512) {
        bool keep = (keepw[i >> 6] >> (i & 63)) & 1ULL;
        out_labels[b * KK + i] = keep ? (float)labs[i] : -1.0f;
        out_scores[b * KK + i] = keep ? (float)dscs[i] : 0.0f;
    }
}

extern "C" void kernel_launch(void* const* d_in, const int* in_sizes, int n_in,
                              void* d_out, int out_size, void* d_ws, size_t ws_size,
                              hipStream_t stream) {
    const float* outs = (const float*)d_in[0];
    float* out = (float*)d_out;
    char* ws = (char*)d_ws;

    uint32_t* keys = (uint32_t*)ws;                            // 6.4 MB
    size_t off = (size_t)BB * NN * 4;
    uint32_t* meta = (uint32_t*)(ws + off);  off += BB * 2 * 4;
    uint32_t* cnt = (uint32_t*)(ws + off);   off += BB * 4;
    uint32_t* candidx = (uint32_t*)(ws + off); off += (size_t)BB * NCAND * 4;
    double* sdsc = (double*)(ws + off);      off += (size_t)BB * KK * 8;
    int* slab = (int*)(ws + off);            off += (size_t)BB * KK * 4;
    ull* bsup = (ull*)(ws + off);            off += (size_t)BB * KK * 8 * 8;

    score_kernel<<<BB * BPB, 512, 0, stream>>>(outs, keys);
    scan_kernel<<<BB, 1024, 0, stream>>>(keys, meta, cnt, candidx);
    ranksup_kernel<<<BB * 8, 1024, 0, stream>>>(outs, keys, cnt, candidx,
                                                sdsc, slab, bsup, out);
    supnms_kernel<<<BB, 512, 0, stream>>>(sdsc, slab, bsup, out);
}